// Round 5
// baseline (139.042 us; speedup 1.0000x reference)
//
#include <hip/hip_runtime.h>

// Problem constants (from reference setup_inputs)
constexpr int NPTS = 8192;   // points per batch
constexpr int NQ   = 2048;   // query points per batch
constexpr int NC   = 64;     // feature channels
constexpr int NS   = 32;     // nsample
constexpr int NCH  = 3 + 1 + NC;           // 68 output channels
constexpr int CS   = NQ * NS;              // channel stride in output (floats)

// Workspace layout (floats):
//   ftr : B*NPTS*NC   transposed features (B,N,C)      @ 0
//   soa : B*3*NPTS    xyz SoA per batch [xs|ys|zs]     @ FTR_FLOATS
//   idx : B*NQ*NS     int32 hit indices                @ FTR_FLOATS+SOA_FLOATS

// R5 = R4 kernels byte-identical; ONLY change is the launcher enqueues
// group_kernel 3x (idempotent) to measure t_group from the dur delta:
//   dur(R5) - dur(R4) = 2*t_group + 2*t_gap

// ---------------------------------------------------------------------------
// K0: prep. blocks 0..127 per batch: 64-pt feature-transpose tile.
//     blocks 128..129 per batch: xyz AoS->SoA (4096 pts each).
// ---------------------------------------------------------------------------
__global__ __launch_bounds__(256, 8) void prep_kernel(
    const float* __restrict__ feat,   // (B, NC, NPTS)
    const float* __restrict__ xyz,    // (B, NPTS, 3)
    float* __restrict__ ftr,          // (B, NPTS, NC)
    float* __restrict__ soa)          // (B, 3, NPTS)
{
    const int b  = blockIdx.y;
    const int bx = blockIdx.x;
    const int t  = threadIdx.x;

    if (bx < NPTS / 64) {
        __shared__ float tile[NC][65];   // +1 pad -> 2-way LDS aliasing (free)
        const int n0 = bx * 64;
        const float* fb = feat + (size_t)b * NC * NPTS;
        {
            const int pl = t & 63;
            const int c0 = t >> 6;
            #pragma unroll
            for (int i = 0; i < 16; ++i) {
                const int c = c0 + 4 * i;
                tile[c][pl] = fb[(size_t)c * NPTS + n0 + pl];
            }
        }
        __syncthreads();
        float* tb = ftr + ((size_t)b * NPTS + n0) * NC;
        {
            const int cl = t & 63;
            const int pb = t >> 6;
            #pragma unroll
            for (int i = 0; i < 16; ++i) {
                const int pp = pb + 4 * i;
                tb[(size_t)pp * NC + cl] = tile[cl][pp];
            }
        }
    } else {
        // SoA: 2 blocks x 256 threads x 16 pts = 8192
        const int n0 = (bx - NPTS / 64) * 4096;
        const float* xb = xyz + (size_t)b * NPTS * 3;
        float* xs = soa + (size_t)b * 3 * NPTS;
        float* ys = xs + NPTS;
        float* zs = ys + NPTS;
        #pragma unroll
        for (int k = 0; k < 16; ++k) {
            const int i = n0 + k * 256 + t;
            xs[i] = xb[i * 3 + 0];
            ys[i] = xb[i * 3 + 1];
            zs[i] = xb[i * 3 + 2];
        }
    }
}

// ---------------------------------------------------------------------------
// K1: ellipsoid ballot-scan, one wave per query, prefetch distance 2.
// Writes idx (global) + output channels 0..3 (xyz, 1/density).
// Strict per-op rounding in the reference's evaluation order: the q<1.0
// compare is discontinuous, so no FMA contraction allowed in the test.
// ---------------------------------------------------------------------------
__global__ __launch_bounds__(256, 8) void scan_kernel(
    const float* __restrict__ soa,    // (B, 3, NPTS)
    const float* __restrict__ nxyz,   // (B, NQ, 3)
    int* __restrict__ gidx,           // (B, NQ, NS)
    float* __restrict__ out)          // (B, NCH, NQ, NS)
{
    __shared__ int idx_s[4][NS];

    const int b    = blockIdx.y;
    const int tid  = threadIdx.x;
    const int lane = tid & 63;
    const int wave = tid >> 6;           // 0..3
    const int p    = blockIdx.x * 4 + wave;

    const float* xs = soa + (size_t)b * 3 * NPTS;
    const float* ys = xs + NPTS;
    const float* zs = ys + NPTS;
    int* idx_row = idx_s[wave];

    const float qx = nxyz[((size_t)b * NQ + p) * 3 + 0];
    const float qy = nxyz[((size_t)b * NQ + p) * 3 + 1];
    const float qz = nxyz[((size_t)b * NQ + p) * 3 + 2];

    int cnt = 0;      // wave-uniform hit count
    int first = -1;   // wave-uniform first-hit index

    float x0 = xs[lane],      y0 = ys[lane],      z0 = zs[lane];
    float x1 = xs[64 + lane], y1 = ys[64 + lane], z1 = zs[64 + lane];

    for (int base = 0; base < NPTS; base += 64) {
        float xn = 0.f, yn = 0.f, zn = 0.f;
        const int pf = base + 128;
        if (pf < NPTS) {
            xn = xs[pf + lane]; yn = ys[pf + lane]; zn = zs[pf + lane];
        }

        const float dx = __fsub_rn(qx, x0);
        const float dy = __fsub_rn(qy, y0);
        const float dz = __fsub_rn(qz, z0);
        const float t0 = __fmul_rn(__fmul_rn(dx, dx), 25.0f);
        const float t1 = __fmul_rn(__fmul_rn(dy, dy), 6.25f);
        const float t2 = __fmul_rn(__fmul_rn(dz, dz), 25.0f);
        const float qv = __fadd_rn(__fadd_rn(t0, t1), t2);
        const bool hit = qv < 1.0f;

        const unsigned long long m = __ballot(hit);
        if (first < 0 && m != 0ull)
            first = base + __builtin_ctzll(m);       // wave-uniform
        if (hit) {
            const int pos = cnt + __popcll(m & ((1ull << lane) - 1ull));
            if (pos < NS) idx_row[pos] = base + lane;
        }
        cnt += __popcll(m);
        if (cnt >= NS) break;                        // uniform early exit

        x0 = x1; y0 = y1; z0 = z1;
        x1 = xn; y1 = yn; z1 = zn;
    }
    if (cnt < NS) {
        const int f = (cnt == 0) ? 0 : first;        // pad (0 if empty)
        if (lane < NS && lane >= cnt) idx_row[lane] = f;
    }

    if (lane < NS) {
        const int s = lane;
        const int j = idx_row[s];                    // same-wave LDS RAW: safe
        gidx[((size_t)b * NQ + p) * NS + s] = j;

        const float px = xs[j], py = ys[j], pz = zs[j];
        const float dx = __fsub_rn(px, qx);
        const float dy = __fsub_rn(py, qy);
        const float dz = __fsub_rn(pz, qz);
        const float d2 = __fadd_rn(__fadd_rn(__fmul_rn(dx, dx), __fmul_rn(dy, dy)),
                                   __fmul_rn(dz, dz));
        const float dist = __fsqrt_rn(d2);
        const float arg  = __fdiv_rn(-__fmul_rn(dist, dist), 0.02f);
        const float density = __fmul_rn(expf(arg), 4.0f);  // /0.25 == *4 exact
        const float gd = __fdiv_rn(1.0f, density);         // inf on underflow == ref

        float* ob = out + ((size_t)b * NCH * NQ + p) * NS + s;
        ob[0 * (size_t)CS] = px;
        ob[1 * (size_t)CS] = py;
        ob[2 * (size_t)CS] = pz;
        ob[3 * (size_t)CS] = gd;
    }
}

// ---------------------------------------------------------------------------
// K2: feature grouping (R4 version, unchanged).
// ---------------------------------------------------------------------------
__global__ __launch_bounds__(512, 8) void group_kernel(
    const int* __restrict__ gidx,     // (B, NQ, NS)
    const float* __restrict__ ftr,    // (B, NPTS, NC)
    float* __restrict__ out,          // (B, NCH, NQ, NS)
    int B)
{
    __shared__ float ldsc[NC][33];

    const int g = blockIdx.x;
    int b, p;
    if (B == 4) {
        b = (g & 7) >> 1;                     // XCD-pair -> batch
        p = ((g >> 3) << 1) | (g & 1);
    } else {
        b = g / NQ;
        p = g - b * NQ;
    }
    const int tid = threadIdx.x;

    // ---- gather phase: lane = (sl, cg) ----
    const int cg = tid & 15;                  // channel group 0..15 (float4)
    const int sl = tid >> 4;                  // sample 0..31
    const int j  = gidx[((size_t)b * NQ + p) * NS + sl];
    const float4 v = ((const float4*)(ftr + ((size_t)b * NPTS + j) * NC))[cg];
    ldsc[4 * cg + 0][sl] = v.x;               // bank (4cg+i+sl)%32 -> 2-way, free
    ldsc[4 * cg + 1][sl] = v.y;
    ldsc[4 * cg + 2][sl] = v.z;
    ldsc[4 * cg + 3][sl] = v.w;
    __syncthreads();

    // ---- store phase: lane = (c, s4) ----
    const int c  = tid >> 3;                  // channel 0..63
    const int s4 = (tid & 7) << 2;            // sample base 0,4,...,28
    float4 w;
    w.x = ldsc[c][s4 + 0];                    // bank (c+s4+i)%32 -> <=2-way, free
    w.y = ldsc[c][s4 + 1];
    w.z = ldsc[c][s4 + 2];
    w.w = ldsc[c][s4 + 3];
    float* op = out + (((size_t)b * NCH + 4 + c) * NQ + p) * NS + s4;
    *(float4*)op = w;                         // 8 x 128B segments per wave store
}

// ---------------------------------------------------------------------------
// Fallback (tiny ws): R1-style fused direct kernel.
// ---------------------------------------------------------------------------
__global__ __launch_bounds__(512, 8) void ellip_direct_kernel(
    const float* __restrict__ xyz,
    const float* __restrict__ nxyz,
    const float* __restrict__ feat,
    float* __restrict__ out)
{
    __shared__ int idx_s[8][NS];

    const int b    = blockIdx.y;
    const int p0   = blockIdx.x * 8;
    const int tid  = threadIdx.x;
    const int lane = tid & 63;
    const int wave = tid >> 6;
    const float* xb = xyz + (size_t)b * NPTS * 3;

    {
        const int p = p0 + wave;
        const float qx = nxyz[((size_t)b * NQ + p) * 3 + 0];
        const float qy = nxyz[((size_t)b * NQ + p) * 3 + 1];
        const float qz = nxyz[((size_t)b * NQ + p) * 3 + 2];
        int cnt = 0, first = -1;
        for (int base = 0; base < NPTS; base += 64) {
            const int i = base + lane;
            const float dx = __fsub_rn(qx, xb[i * 3 + 0]);
            const float dy = __fsub_rn(qy, xb[i * 3 + 1]);
            const float dz = __fsub_rn(qz, xb[i * 3 + 2]);
            const float t0 = __fmul_rn(__fmul_rn(dx, dx), 25.0f);
            const float t1 = __fmul_rn(__fmul_rn(dy, dy), 6.25f);
            const float t2 = __fmul_rn(__fmul_rn(dz, dz), 25.0f);
            const float qv = __fadd_rn(__fadd_rn(t0, t1), t2);
            const bool hit = qv < 1.0f;
            const unsigned long long m = __ballot(hit);
            if (first < 0 && m != 0ull) first = base + __builtin_ctzll(m);
            if (hit) {
                const int pos = cnt + __popcll(m & ((1ull << lane) - 1ull));
                if (pos < NS) idx_s[wave][pos] = i;
            }
            cnt += __popcll(m);
            if (cnt >= NS) break;
        }
        if (cnt < NS) {
            const int f = (cnt == 0) ? 0 : first;
            if (lane < NS && lane >= cnt) idx_s[wave][lane] = f;
        }
    }
    __syncthreads();

    const int s = tid & 31;
    const int h = (tid >> 5) & 1;
    const int q = tid >> 6;
    const int p = p0 + q;
    const int j = idx_s[q][s];
    float* ob = out + ((size_t)b * NCH * NQ + p) * NS + s;

    if (h == 0) {
        const float qx = nxyz[((size_t)b * NQ + p) * 3 + 0];
        const float qy = nxyz[((size_t)b * NQ + p) * 3 + 1];
        const float qz = nxyz[((size_t)b * NQ + p) * 3 + 2];
        const float px = xb[j * 3 + 0], py = xb[j * 3 + 1], pz = xb[j * 3 + 2];
        const float dx = __fsub_rn(px, qx);
        const float dy = __fsub_rn(py, qy);
        const float dz = __fsub_rn(pz, qz);
        const float d2 = __fadd_rn(__fadd_rn(__fmul_rn(dx, dx), __fmul_rn(dy, dy)),
                                   __fmul_rn(dz, dz));
        const float dist = __fsqrt_rn(d2);
        const float arg  = __fdiv_rn(-__fmul_rn(dist, dist), 0.02f);
        const float gd = __fdiv_rn(1.0f, __fmul_rn(expf(arg), 4.0f));
        ob[0 * (size_t)CS] = px;
        ob[1 * (size_t)CS] = py;
        ob[2 * (size_t)CS] = pz;
        ob[3 * (size_t)CS] = gd;
    }
    const float* fb = feat + (size_t)b * NC * NPTS + j;
    #pragma unroll 4
    for (int c = h; c < NC; c += 2)
        ob[(size_t)(4 + c) * CS] = fb[(size_t)c * NPTS];
}

extern "C" void kernel_launch(void* const* d_in, const int* in_sizes, int n_in,
                              void* d_out, int out_size, void* d_ws, size_t ws_size,
                              hipStream_t stream) {
    const float* xyz  = (const float*)d_in[0];   // (B, 8192, 3)
    const float* nxyz = (const float*)d_in[1];   // (B, 2048, 3)
    const float* feat = (const float*)d_in[2];   // (B, 64, 8192)
    float* out = (float*)d_out;                  // (B, 68, 2048, 32)

    const int B = in_sizes[0] / (NPTS * 3);
    const size_t ftr_f = (size_t)B * NPTS * NC;
    const size_t soa_f = (size_t)B * 3 * NPTS;
    const size_t idx_f = (size_t)B * NQ * NS;
    const size_t need  = (ftr_f + soa_f + idx_f) * 4;

    if (ws_size >= need) {
        float* ftr = (float*)d_ws;
        float* soa = ftr + ftr_f;
        int*   idx = (int*)(soa + soa_f);

        prep_kernel<<<dim3(NPTS / 64 + 2, B), 256, 0, stream>>>(feat, xyz, ftr, soa);
        scan_kernel<<<dim3(NQ / 4, B), 256, 0, stream>>>(soa, nxyz, idx, out);
        // DIAGNOSTIC (R5): group launched 3x, idempotent. dur delta vs R4
        // = 2*t_group + 2*t_gap. Kernels byte-identical to R4.
        group_kernel<<<dim3(B * NQ), 512, 0, stream>>>(idx, ftr, out, B);
        group_kernel<<<dim3(B * NQ), 512, 0, stream>>>(idx, ftr, out, B);
        group_kernel<<<dim3(B * NQ), 512, 0, stream>>>(idx, ftr, out, B);
    } else {
        ellip_direct_kernel<<<dim3(NQ / 8, B), 512, 0, stream>>>(xyz, nxyz, feat, out);
    }
}

// Round 6
// 137.725 us; speedup vs baseline: 1.0096x; 1.0096x over previous
//
#include <hip/hip_runtime.h>

// Problem constants (from reference setup_inputs)
constexpr int NPTS = 8192;   // points per batch
constexpr int NQ   = 2048;   // query points per batch
constexpr int NC   = 64;     // feature channels
constexpr int NS   = 32;     // nsample
constexpr int NCH  = 3 + 1 + NC;           // 68 output channels
constexpr int CS   = NQ * NS;              // channel stride in output (floats)

// Workspace layout (floats):
//   ftr : B*NPTS*NC   transposed features (B,N,C)      @ 0
//   soa : B*3*NPTS    xyz SoA per batch [xs|ys|zs]     @ FTR_FLOATS
//   idx : B*NQ*NS     int32 hit indices                @ FTR_FLOATS+SOA_FLOATS

// R6 = R4 kernels byte-identical; ONLY change is the launcher enqueues
// scan_kernel 3x (idempotent) to measure t_scan from the dur delta:
//   dur(R6) - dur(R4) = 2*t_scan + 2*t_gap
// (R5 measured group+gap = 13.4 us via the same method.)

// ---------------------------------------------------------------------------
// K0: prep. blocks 0..127 per batch: 64-pt feature-transpose tile.
//     blocks 128..129 per batch: xyz AoS->SoA (4096 pts each).
// ---------------------------------------------------------------------------
__global__ __launch_bounds__(256, 8) void prep_kernel(
    const float* __restrict__ feat,   // (B, NC, NPTS)
    const float* __restrict__ xyz,    // (B, NPTS, 3)
    float* __restrict__ ftr,          // (B, NPTS, NC)
    float* __restrict__ soa)          // (B, 3, NPTS)
{
    const int b  = blockIdx.y;
    const int bx = blockIdx.x;
    const int t  = threadIdx.x;

    if (bx < NPTS / 64) {
        __shared__ float tile[NC][65];   // +1 pad -> 2-way LDS aliasing (free)
        const int n0 = bx * 64;
        const float* fb = feat + (size_t)b * NC * NPTS;
        {
            const int pl = t & 63;
            const int c0 = t >> 6;
            #pragma unroll
            for (int i = 0; i < 16; ++i) {
                const int c = c0 + 4 * i;
                tile[c][pl] = fb[(size_t)c * NPTS + n0 + pl];
            }
        }
        __syncthreads();
        float* tb = ftr + ((size_t)b * NPTS + n0) * NC;
        {
            const int cl = t & 63;
            const int pb = t >> 6;
            #pragma unroll
            for (int i = 0; i < 16; ++i) {
                const int pp = pb + 4 * i;
                tb[(size_t)pp * NC + cl] = tile[cl][pp];
            }
        }
    } else {
        // SoA: 2 blocks x 256 threads x 16 pts = 8192
        const int n0 = (bx - NPTS / 64) * 4096;
        const float* xb = xyz + (size_t)b * NPTS * 3;
        float* xs = soa + (size_t)b * 3 * NPTS;
        float* ys = xs + NPTS;
        float* zs = ys + NPTS;
        #pragma unroll
        for (int k = 0; k < 16; ++k) {
            const int i = n0 + k * 256 + t;
            xs[i] = xb[i * 3 + 0];
            ys[i] = xb[i * 3 + 1];
            zs[i] = xb[i * 3 + 2];
        }
    }
}

// ---------------------------------------------------------------------------
// K1: ellipsoid ballot-scan, one wave per query, prefetch distance 2.
// Writes idx (global) + output channels 0..3 (xyz, 1/density).
// Strict per-op rounding in the reference's evaluation order: the q<1.0
// compare is discontinuous, so no FMA contraction allowed in the test.
// ---------------------------------------------------------------------------
__global__ __launch_bounds__(256, 8) void scan_kernel(
    const float* __restrict__ soa,    // (B, 3, NPTS)
    const float* __restrict__ nxyz,   // (B, NQ, 3)
    int* __restrict__ gidx,           // (B, NQ, NS)
    float* __restrict__ out)          // (B, NCH, NQ, NS)
{
    __shared__ int idx_s[4][NS];

    const int b    = blockIdx.y;
    const int tid  = threadIdx.x;
    const int lane = tid & 63;
    const int wave = tid >> 6;           // 0..3
    const int p    = blockIdx.x * 4 + wave;

    const float* xs = soa + (size_t)b * 3 * NPTS;
    const float* ys = xs + NPTS;
    const float* zs = ys + NPTS;
    int* idx_row = idx_s[wave];

    const float qx = nxyz[((size_t)b * NQ + p) * 3 + 0];
    const float qy = nxyz[((size_t)b * NQ + p) * 3 + 1];
    const float qz = nxyz[((size_t)b * NQ + p) * 3 + 2];

    int cnt = 0;      // wave-uniform hit count
    int first = -1;   // wave-uniform first-hit index

    float x0 = xs[lane],      y0 = ys[lane],      z0 = zs[lane];
    float x1 = xs[64 + lane], y1 = ys[64 + lane], z1 = zs[64 + lane];

    for (int base = 0; base < NPTS; base += 64) {
        float xn = 0.f, yn = 0.f, zn = 0.f;
        const int pf = base + 128;
        if (pf < NPTS) {
            xn = xs[pf + lane]; yn = ys[pf + lane]; zn = zs[pf + lane];
        }

        const float dx = __fsub_rn(qx, x0);
        const float dy = __fsub_rn(qy, y0);
        const float dz = __fsub_rn(qz, z0);
        const float t0 = __fmul_rn(__fmul_rn(dx, dx), 25.0f);
        const float t1 = __fmul_rn(__fmul_rn(dy, dy), 6.25f);
        const float t2 = __fmul_rn(__fmul_rn(dz, dz), 25.0f);
        const float qv = __fadd_rn(__fadd_rn(t0, t1), t2);
        const bool hit = qv < 1.0f;

        const unsigned long long m = __ballot(hit);
        if (first < 0 && m != 0ull)
            first = base + __builtin_ctzll(m);       // wave-uniform
        if (hit) {
            const int pos = cnt + __popcll(m & ((1ull << lane) - 1ull));
            if (pos < NS) idx_row[pos] = base + lane;
        }
        cnt += __popcll(m);
        if (cnt >= NS) break;                        // uniform early exit

        x0 = x1; y0 = y1; z0 = z1;
        x1 = xn; y1 = yn; z1 = zn;
    }
    if (cnt < NS) {
        const int f = (cnt == 0) ? 0 : first;        // pad (0 if empty)
        if (lane < NS && lane >= cnt) idx_row[lane] = f;
    }

    if (lane < NS) {
        const int s = lane;
        const int j = idx_row[s];                    // same-wave LDS RAW: safe
        gidx[((size_t)b * NQ + p) * NS + s] = j;

        const float px = xs[j], py = ys[j], pz = zs[j];
        const float dx = __fsub_rn(px, qx);
        const float dy = __fsub_rn(py, qy);
        const float dz = __fsub_rn(pz, qz);
        const float d2 = __fadd_rn(__fadd_rn(__fmul_rn(dx, dx), __fmul_rn(dy, dy)),
                                   __fmul_rn(dz, dz));
        const float dist = __fsqrt_rn(d2);
        const float arg  = __fdiv_rn(-__fmul_rn(dist, dist), 0.02f);
        const float density = __fmul_rn(expf(arg), 4.0f);  // /0.25 == *4 exact
        const float gd = __fdiv_rn(1.0f, density);         // inf on underflow == ref

        float* ob = out + ((size_t)b * NCH * NQ + p) * NS + s;
        ob[0 * (size_t)CS] = px;
        ob[1 * (size_t)CS] = py;
        ob[2 * (size_t)CS] = pz;
        ob[3 * (size_t)CS] = gd;
    }
}

// ---------------------------------------------------------------------------
// K2: feature grouping (R4 version, unchanged).
// ---------------------------------------------------------------------------
__global__ __launch_bounds__(512, 8) void group_kernel(
    const int* __restrict__ gidx,     // (B, NQ, NS)
    const float* __restrict__ ftr,    // (B, NPTS, NC)
    float* __restrict__ out,          // (B, NCH, NQ, NS)
    int B)
{
    __shared__ float ldsc[NC][33];

    const int g = blockIdx.x;
    int b, p;
    if (B == 4) {
        b = (g & 7) >> 1;                     // XCD-pair -> batch
        p = ((g >> 3) << 1) | (g & 1);
    } else {
        b = g / NQ;
        p = g - b * NQ;
    }
    const int tid = threadIdx.x;

    // ---- gather phase: lane = (sl, cg) ----
    const int cg = tid & 15;                  // channel group 0..15 (float4)
    const int sl = tid >> 4;                  // sample 0..31
    const int j  = gidx[((size_t)b * NQ + p) * NS + sl];
    const float4 v = ((const float4*)(ftr + ((size_t)b * NPTS + j) * NC))[cg];
    ldsc[4 * cg + 0][sl] = v.x;               // bank (4cg+i+sl)%32 -> 2-way, free
    ldsc[4 * cg + 1][sl] = v.y;
    ldsc[4 * cg + 2][sl] = v.z;
    ldsc[4 * cg + 3][sl] = v.w;
    __syncthreads();

    // ---- store phase: lane = (c, s4) ----
    const int c  = tid >> 3;                  // channel 0..63
    const int s4 = (tid & 7) << 2;            // sample base 0,4,...,28
    float4 w;
    w.x = ldsc[c][s4 + 0];                    // bank (c+s4+i)%32 -> <=2-way, free
    w.y = ldsc[c][s4 + 1];
    w.z = ldsc[c][s4 + 2];
    w.w = ldsc[c][s4 + 3];
    float* op = out + (((size_t)b * NCH + 4 + c) * NQ + p) * NS + s4;
    *(float4*)op = w;                         // 8 x 128B segments per wave store
}

// ---------------------------------------------------------------------------
// Fallback (tiny ws): R1-style fused direct kernel.
// ---------------------------------------------------------------------------
__global__ __launch_bounds__(512, 8) void ellip_direct_kernel(
    const float* __restrict__ xyz,
    const float* __restrict__ nxyz,
    const float* __restrict__ feat,
    float* __restrict__ out)
{
    __shared__ int idx_s[8][NS];

    const int b    = blockIdx.y;
    const int p0   = blockIdx.x * 8;
    const int tid  = threadIdx.x;
    const int lane = tid & 63;
    const int wave = tid >> 6;
    const float* xb = xyz + (size_t)b * NPTS * 3;

    {
        const int p = p0 + wave;
        const float qx = nxyz[((size_t)b * NQ + p) * 3 + 0];
        const float qy = nxyz[((size_t)b * NQ + p) * 3 + 1];
        const float qz = nxyz[((size_t)b * NQ + p) * 3 + 2];
        int cnt = 0, first = -1;
        for (int base = 0; base < NPTS; base += 64) {
            const int i = base + lane;
            const float dx = __fsub_rn(qx, xb[i * 3 + 0]);
            const float dy = __fsub_rn(qy, xb[i * 3 + 1]);
            const float dz = __fsub_rn(qz, xb[i * 3 + 2]);
            const float t0 = __fmul_rn(__fmul_rn(dx, dx), 25.0f);
            const float t1 = __fmul_rn(__fmul_rn(dy, dy), 6.25f);
            const float t2 = __fmul_rn(__fmul_rn(dz, dz), 25.0f);
            const float qv = __fadd_rn(__fadd_rn(t0, t1), t2);
            const bool hit = qv < 1.0f;
            const unsigned long long m = __ballot(hit);
            if (first < 0 && m != 0ull) first = base + __builtin_ctzll(m);
            if (hit) {
                const int pos = cnt + __popcll(m & ((1ull << lane) - 1ull));
                if (pos < NS) idx_s[wave][pos] = i;
            }
            cnt += __popcll(m);
            if (cnt >= NS) break;
        }
        if (cnt < NS) {
            const int f = (cnt == 0) ? 0 : first;
            if (lane < NS && lane >= cnt) idx_s[wave][lane] = f;
        }
    }
    __syncthreads();

    const int s = tid & 31;
    const int h = (tid >> 5) & 1;
    const int q = tid >> 6;
    const int p = p0 + q;
    const int j = idx_s[q][s];
    float* ob = out + ((size_t)b * NCH * NQ + p) * NS + s;

    if (h == 0) {
        const float qx = nxyz[((size_t)b * NQ + p) * 3 + 0];
        const float qy = nxyz[((size_t)b * NQ + p) * 3 + 1];
        const float qz = nxyz[((size_t)b * NQ + p) * 3 + 2];
        const float px = xb[j * 3 + 0], py = xb[j * 3 + 1], pz = xb[j * 3 + 2];
        const float dx = __fsub_rn(px, qx);
        const float dy = __fsub_rn(py, qy);
        const float dz = __fsub_rn(pz, qz);
        const float d2 = __fadd_rn(__fadd_rn(__fmul_rn(dx, dx), __fmul_rn(dy, dy)),
                                   __fmul_rn(dz, dz));
        const float dist = __fsqrt_rn(d2);
        const float arg  = __fdiv_rn(-__fmul_rn(dist, dist), 0.02f);
        const float gd = __fdiv_rn(1.0f, __fmul_rn(expf(arg), 4.0f));
        ob[0 * (size_t)CS] = px;
        ob[1 * (size_t)CS] = py;
        ob[2 * (size_t)CS] = pz;
        ob[3 * (size_t)CS] = gd;
    }
    const float* fb = feat + (size_t)b * NC * NPTS + j;
    #pragma unroll 4
    for (int c = h; c < NC; c += 2)
        ob[(size_t)(4 + c) * CS] = fb[(size_t)c * NPTS];
}

extern "C" void kernel_launch(void* const* d_in, const int* in_sizes, int n_in,
                              void* d_out, int out_size, void* d_ws, size_t ws_size,
                              hipStream_t stream) {
    const float* xyz  = (const float*)d_in[0];   // (B, 8192, 3)
    const float* nxyz = (const float*)d_in[1];   // (B, 2048, 3)
    const float* feat = (const float*)d_in[2];   // (B, 64, 8192)
    float* out = (float*)d_out;                  // (B, 68, 2048, 32)

    const int B = in_sizes[0] / (NPTS * 3);
    const size_t ftr_f = (size_t)B * NPTS * NC;
    const size_t soa_f = (size_t)B * 3 * NPTS;
    const size_t idx_f = (size_t)B * NQ * NS;
    const size_t need  = (ftr_f + soa_f + idx_f) * 4;

    if (ws_size >= need) {
        float* ftr = (float*)d_ws;
        float* soa = ftr + ftr_f;
        int*   idx = (int*)(soa + soa_f);

        prep_kernel<<<dim3(NPTS / 64 + 2, B), 256, 0, stream>>>(feat, xyz, ftr, soa);
        // DIAGNOSTIC (R6): scan launched 3x, idempotent. dur delta vs R4
        // = 2*t_scan + 2*t_gap. Kernels byte-identical to R4.
        scan_kernel<<<dim3(NQ / 4, B), 256, 0, stream>>>(soa, nxyz, idx, out);
        scan_kernel<<<dim3(NQ / 4, B), 256, 0, stream>>>(soa, nxyz, idx, out);
        scan_kernel<<<dim3(NQ / 4, B), 256, 0, stream>>>(soa, nxyz, idx, out);
        group_kernel<<<dim3(B * NQ), 512, 0, stream>>>(idx, ftr, out, B);
    } else {
        ellip_direct_kernel<<<dim3(NQ / 8, B), 512, 0, stream>>>(xyz, nxyz, feat, out);
    }
}

// Round 7
// 102.656 us; speedup vs baseline: 1.3544x; 1.3416x over previous
//
#include <hip/hip_runtime.h>

// Problem constants (from reference setup_inputs)
constexpr int NPTS = 8192;   // points per batch
constexpr int NQ   = 2048;   // query points per batch
constexpr int NC   = 64;     // feature channels
constexpr int NS   = 32;     // nsample
constexpr int NCH  = 3 + 1 + NC;           // 68 output channels
constexpr int CS   = NQ * NS;              // channel stride in output (floats)
constexpr int LPTS = 4096;   // points staged in LDS (48 KB; rest via global tail)
constexpr int QPB2 = 16;     // queries per scan block (16 waves, 1024 thr)

// Workspace layout (floats):  ftr : B*NPTS*NC  |  idx : B*NQ*NS (int32)

// Union LDS: scan blocks use pts+idx (50 KB); transpose blocks use tile (33 KB).
struct ScanLds { float pts[3][LPTS]; int idx[QPB2][NS]; };
union  KLds    { ScanLds s; float tile[2][NC][65]; };

// ---------------------------------------------------------------------------
// K1: fused [feature-transpose blocks | ellipsoid-scan blocks].
// Transpose blocks come FIRST in dispatch order so their BW work overlaps the
// scan blocks' compute. No inter-block dependencies inside this kernel:
// transpose reads feat->writes ftr; scan reads xyz/nxyz->writes gidx + ch0..3.
// Strict per-op rounding in the reference's evaluation order for the q<1.0
// test (discontinuous -> no FMA contraction allowed).
// ---------------------------------------------------------------------------
__global__ __launch_bounds__(1024, 8) void scan_trans_kernel(
    const float* __restrict__ xyz,    // (B, NPTS, 3)
    const float* __restrict__ nxyz,   // (B, NQ, 3)
    const float* __restrict__ feat,   // (B, NC, NPTS)
    float* __restrict__ ftr,          // (B, NPTS, NC)
    int* __restrict__ gidx,           // (B, NQ, NS)
    float* __restrict__ out,          // (B, NCH, NQ, NS)
    int ntrans)
{
    __shared__ KLds u;
    const int bx = blockIdx.x;
    const int t  = threadIdx.x;

    if (bx < ntrans) {
        // ---- feature transpose: 2 tiles of 64 points, 512 thr each ----
        const int b   = bx >> 6;              // 64 t-blocks per batch
        const int tl2 = bx & 63;
        const int h   = t >> 9;               // tile half 0/1
        const int v   = t & 511;
        const int pl  = v & 63;               // lane within 64-pt tile
        const int c0  = v >> 6;               // 0..7 (wave-uniform)
        const int n0  = tl2 * 128 + h * 64;
        const float* fb = feat + (size_t)b * NC * NPTS;
        #pragma unroll
        for (int i = 0; i < 8; ++i) {         // loads coalesced 256B/row
            const int c = c0 + 8 * i;
            u.tile[h][c][pl] = fb[(size_t)c * NPTS + n0 + pl];  // bank lane%32: free
        }
        __syncthreads();
        float* tb = ftr + ((size_t)b * NPTS + n0) * NC;
        #pragma unroll
        for (int i = 0; i < 8; ++i) {         // stores coalesced 256B/point
            const int pp = c0 + 8 * i;
            tb[(size_t)pp * NC + pl] = u.tile[h][pl][pp];       // (lane*65+k)%32: free
        }
        return;
    }

    // ---- scan block: 16 queries, LDS-staged first-4096 points ----
    const int sb   = bx - ntrans;
    const int qpb  = NQ / QPB2;               // 128 scan-blocks per batch
    const int b    = sb / qpb;
    const int p0   = (sb - b * qpb) * QPB2;
    const int lane = t & 63;
    const int wave = t >> 6;                  // 0..15
    const float* xb = xyz + (size_t)b * NPTS * 3;

    // stage pts[3][LPTS] from AoS: 12288 dwords, 12 per thread, coalesced reads;
    // LDS writes ~6-way bank (3 coords alias) -> ~2x cost, ~150 cyc/wave total.
    #pragma unroll
    for (int k = 0; k < 3 * LPTS / 1024; ++k) {
        const int g  = k * 1024 + t;
        const float val = xb[g];
        const int pt = g / 3;                 // magic-mul
        const int c  = g - 3 * pt;
        u.s.pts[c][pt] = val;
    }
    __syncthreads();

    const int p = p0 + wave;
    const float qx = nxyz[((size_t)b * NQ + p) * 3 + 0];
    const float qy = nxyz[((size_t)b * NQ + p) * 3 + 1];
    const float qz = nxyz[((size_t)b * NQ + p) * 3 + 2];

    int cnt = 0;      // wave-uniform hit count
    int first = -1;   // wave-uniform first-hit index
    int* idx_row = u.s.idx[wave];

    // phase A: LDS points 0..LPTS-1
    for (int base = 0; base < LPTS; base += 64) {
        const int i = base + lane;
        const float x = u.s.pts[0][i];        // bank (base+lane)%32: 2-way, free
        const float y = u.s.pts[1][i];
        const float z = u.s.pts[2][i];
        const float dx = __fsub_rn(qx, x);
        const float dy = __fsub_rn(qy, y);
        const float dz = __fsub_rn(qz, z);
        const float t0 = __fmul_rn(__fmul_rn(dx, dx), 25.0f);
        const float t1 = __fmul_rn(__fmul_rn(dy, dy), 6.25f);
        const float t2 = __fmul_rn(__fmul_rn(dz, dz), 25.0f);
        const float qv = __fadd_rn(__fadd_rn(t0, t1), t2);
        const bool hit = qv < 1.0f;

        const unsigned long long m = __ballot(hit);
        if (first < 0 && m != 0ull)
            first = base + __builtin_ctzll(m);       // wave-uniform
        if (hit) {
            const int pos = cnt + __popcll(m & ((1ull << lane) - 1ull));
            if (pos < NS) idx_row[pos] = i;
        }
        cnt += __popcll(m);
        if (cnt >= NS) break;                        // uniform early exit
    }

    // phase B (rare, deep-corner queries): global tail with prefetch-2
    if (cnt < NS) {
        float x0 = xb[3 * (LPTS + lane) + 0];
        float y0 = xb[3 * (LPTS + lane) + 1];
        float z0 = xb[3 * (LPTS + lane) + 2];
        float x1 = xb[3 * (LPTS + 64 + lane) + 0];
        float y1 = xb[3 * (LPTS + 64 + lane) + 1];
        float z1 = xb[3 * (LPTS + 64 + lane) + 2];
        for (int base = LPTS; base < NPTS; base += 64) {
            float xn = 0.f, yn = 0.f, zn = 0.f;
            const int pf = base + 128;
            if (pf < NPTS) {
                xn = xb[3 * (pf + lane) + 0];
                yn = xb[3 * (pf + lane) + 1];
                zn = xb[3 * (pf + lane) + 2];
            }
            const float dx = __fsub_rn(qx, x0);
            const float dy = __fsub_rn(qy, y0);
            const float dz = __fsub_rn(qz, z0);
            const float t0 = __fmul_rn(__fmul_rn(dx, dx), 25.0f);
            const float t1 = __fmul_rn(__fmul_rn(dy, dy), 6.25f);
            const float t2 = __fmul_rn(__fmul_rn(dz, dz), 25.0f);
            const float qv = __fadd_rn(__fadd_rn(t0, t1), t2);
            const bool hit = qv < 1.0f;

            const unsigned long long m = __ballot(hit);
            if (first < 0 && m != 0ull)
                first = base + __builtin_ctzll(m);
            if (hit) {
                const int pos = cnt + __popcll(m & ((1ull << lane) - 1ull));
                if (pos < NS) idx_row[pos] = base + lane;
            }
            cnt += __popcll(m);
            if (cnt >= NS) break;
            x0 = x1; y0 = y1; z0 = z1;
            x1 = xn; y1 = yn; z1 = zn;
        }
    }

    if (cnt < NS) {
        const int f = (cnt == 0) ? 0 : first;        // pad (0 if empty)
        if (lane < NS && lane >= cnt) idx_row[lane] = f;
    }

    // epilogue: lanes 0..31 emit idx + channels 0..3
    if (lane < NS) {
        const int s = lane;
        const int j = idx_row[s];                    // same-wave LDS RAW: safe
        gidx[((size_t)b * NQ + p) * NS + s] = j;

        const float px = xb[3 * j + 0];
        const float py = xb[3 * j + 1];
        const float pz = xb[3 * j + 2];
        const float dx = __fsub_rn(px, qx);
        const float dy = __fsub_rn(py, qy);
        const float dz = __fsub_rn(pz, qz);
        const float d2 = __fadd_rn(__fadd_rn(__fmul_rn(dx, dx), __fmul_rn(dy, dy)),
                                   __fmul_rn(dz, dz));
        const float dist = __fsqrt_rn(d2);
        const float arg  = __fdiv_rn(-__fmul_rn(dist, dist), 0.02f);
        const float density = __fmul_rn(expf(arg), 4.0f);  // /0.25 == *4 exact
        const float gd = __fdiv_rn(1.0f, density);         // inf on underflow == ref

        float* ob = out + ((size_t)b * NCH * NQ + p) * NS + s;
        ob[0 * (size_t)CS] = px;
        ob[1 * (size_t)CS] = py;
        ob[2 * (size_t)CS] = pz;
        ob[3 * (size_t)CS] = gd;
    }
}

// ---------------------------------------------------------------------------
// K2: feature grouping (R4 version, measured at write-BW floor ~11-13 us).
// ---------------------------------------------------------------------------
__global__ __launch_bounds__(512, 8) void group_kernel(
    const int* __restrict__ gidx,     // (B, NQ, NS)
    const float* __restrict__ ftr,    // (B, NPTS, NC)
    float* __restrict__ out,          // (B, NCH, NQ, NS)
    int B)
{
    __shared__ float ldsc[NC][33];

    const int g = blockIdx.x;
    int b, p;
    if (B == 4) {
        b = (g & 7) >> 1;                     // XCD-pair -> batch
        p = ((g >> 3) << 1) | (g & 1);
    } else {
        b = g / NQ;
        p = g - b * NQ;
    }
    const int tid = threadIdx.x;

    // ---- gather phase: lane = (sl, cg) ----
    const int cg = tid & 15;                  // channel group 0..15 (float4)
    const int sl = tid >> 4;                  // sample 0..31
    const int j  = gidx[((size_t)b * NQ + p) * NS + sl];
    const float4 v = ((const float4*)(ftr + ((size_t)b * NPTS + j) * NC))[cg];
    ldsc[4 * cg + 0][sl] = v.x;               // bank (4cg+i+sl)%32 -> 2-way, free
    ldsc[4 * cg + 1][sl] = v.y;
    ldsc[4 * cg + 2][sl] = v.z;
    ldsc[4 * cg + 3][sl] = v.w;
    __syncthreads();

    // ---- store phase: lane = (c, s4) ----
    const int c  = tid >> 3;                  // channel 0..63
    const int s4 = (tid & 7) << 2;            // sample base 0,4,...,28
    float4 w;
    w.x = ldsc[c][s4 + 0];                    // bank (c+s4+i)%32 -> <=2-way, free
    w.y = ldsc[c][s4 + 1];
    w.z = ldsc[c][s4 + 2];
    w.w = ldsc[c][s4 + 3];
    float* op = out + (((size_t)b * NCH + 4 + c) * NQ + p) * NS + s4;
    *(float4*)op = w;                         // 8 x 128B segments per wave store
}

// ---------------------------------------------------------------------------
// Fallback (tiny ws): R1-style fused direct kernel.
// ---------------------------------------------------------------------------
__global__ __launch_bounds__(512, 8) void ellip_direct_kernel(
    const float* __restrict__ xyz,
    const float* __restrict__ nxyz,
    const float* __restrict__ feat,
    float* __restrict__ out)
{
    __shared__ int idx_s[8][NS];

    const int b    = blockIdx.y;
    const int p0   = blockIdx.x * 8;
    const int tid  = threadIdx.x;
    const int lane = tid & 63;
    const int wave = tid >> 6;
    const float* xb = xyz + (size_t)b * NPTS * 3;

    {
        const int p = p0 + wave;
        const float qx = nxyz[((size_t)b * NQ + p) * 3 + 0];
        const float qy = nxyz[((size_t)b * NQ + p) * 3 + 1];
        const float qz = nxyz[((size_t)b * NQ + p) * 3 + 2];
        int cnt = 0, first = -1;
        for (int base = 0; base < NPTS; base += 64) {
            const int i = base + lane;
            const float dx = __fsub_rn(qx, xb[i * 3 + 0]);
            const float dy = __fsub_rn(qy, xb[i * 3 + 1]);
            const float dz = __fsub_rn(qz, xb[i * 3 + 2]);
            const float t0 = __fmul_rn(__fmul_rn(dx, dx), 25.0f);
            const float t1 = __fmul_rn(__fmul_rn(dy, dy), 6.25f);
            const float t2 = __fmul_rn(__fmul_rn(dz, dz), 25.0f);
            const float qv = __fadd_rn(__fadd_rn(t0, t1), t2);
            const bool hit = qv < 1.0f;
            const unsigned long long m = __ballot(hit);
            if (first < 0 && m != 0ull) first = base + __builtin_ctzll(m);
            if (hit) {
                const int pos = cnt + __popcll(m & ((1ull << lane) - 1ull));
                if (pos < NS) idx_s[wave][pos] = i;
            }
            cnt += __popcll(m);
            if (cnt >= NS) break;
        }
        if (cnt < NS) {
            const int f = (cnt == 0) ? 0 : first;
            if (lane < NS && lane >= cnt) idx_s[wave][lane] = f;
        }
    }
    __syncthreads();

    const int s = tid & 31;
    const int h = (tid >> 5) & 1;
    const int q = tid >> 6;
    const int p = p0 + q;
    const int j = idx_s[q][s];
    float* ob = out + ((size_t)b * NCH * NQ + p) * NS + s;

    if (h == 0) {
        const float qx = nxyz[((size_t)b * NQ + p) * 3 + 0];
        const float qy = nxyz[((size_t)b * NQ + p) * 3 + 1];
        const float qz = nxyz[((size_t)b * NQ + p) * 3 + 2];
        const float px = xb[j * 3 + 0], py = xb[j * 3 + 1], pz = xb[j * 3 + 2];
        const float dx = __fsub_rn(px, qx);
        const float dy = __fsub_rn(py, qy);
        const float dz = __fsub_rn(pz, qz);
        const float d2 = __fadd_rn(__fadd_rn(__fmul_rn(dx, dx), __fmul_rn(dy, dy)),
                                   __fmul_rn(dz, dz));
        const float dist = __fsqrt_rn(d2);
        const float arg  = __fdiv_rn(-__fmul_rn(dist, dist), 0.02f);
        const float gd = __fdiv_rn(1.0f, __fmul_rn(expf(arg), 4.0f));
        ob[0 * (size_t)CS] = px;
        ob[1 * (size_t)CS] = py;
        ob[2 * (size_t)CS] = pz;
        ob[3 * (size_t)CS] = gd;
    }
    const float* fb = feat + (size_t)b * NC * NPTS + j;
    #pragma unroll 4
    for (int c = h; c < NC; c += 2)
        ob[(size_t)(4 + c) * CS] = fb[(size_t)c * NPTS];
}

extern "C" void kernel_launch(void* const* d_in, const int* in_sizes, int n_in,
                              void* d_out, int out_size, void* d_ws, size_t ws_size,
                              hipStream_t stream) {
    const float* xyz  = (const float*)d_in[0];   // (B, 8192, 3)
    const float* nxyz = (const float*)d_in[1];   // (B, 2048, 3)
    const float* feat = (const float*)d_in[2];   // (B, 64, 8192)
    float* out = (float*)d_out;                  // (B, 68, 2048, 32)

    const int B = in_sizes[0] / (NPTS * 3);
    const size_t ftr_f = (size_t)B * NPTS * NC;
    const size_t idx_f = (size_t)B * NQ * NS;
    const size_t need  = (ftr_f + idx_f) * 4;

    if (ws_size >= need) {
        float* ftr = (float*)d_ws;
        int*   idx = (int*)(ftr + ftr_f);

        const int ntrans = B * 64;               // transpose blocks (first)
        const int nscan  = B * (NQ / QPB2);      // scan blocks
        scan_trans_kernel<<<dim3(ntrans + nscan), 1024, 0, stream>>>(
            xyz, nxyz, feat, ftr, idx, out, ntrans);
        group_kernel<<<dim3(B * NQ), 512, 0, stream>>>(idx, ftr, out, B);
    } else {
        ellip_direct_kernel<<<dim3(NQ / 8, B), 512, 0, stream>>>(xyz, nxyz, feat, out);
    }
}